// Round 11
// baseline (1248.220 us; speedup 1.0000x reference)
//
#include <hip/hip_runtime.h>
#include <hip/hip_bf16.h>
#include <cstdint>

typedef __attribute__((ext_vector_type(8))) short short8;
typedef __attribute__((ext_vector_type(4))) float f32x4;
typedef unsigned short u16;
typedef unsigned int u32;

#define Mdim 1024
#define Ddim 768
#define Edim 100
#define DD (Ddim * Ddim)
#define NW8 7372800   // Edim*DD/8

__device__ __forceinline__ u16 f2bf(float f) {
  u32 u = __builtin_bit_cast(u32, f);
  u += 0x7fffu + ((u >> 16) & 1u);   // RNE
  return (u16)(u >> 16);
}
__device__ __forceinline__ float bf2f(u16 h) {
  return __builtin_bit_cast(float, ((u32)h) << 16);
}
__device__ __forceinline__ u32 pack2(float a, float b) {
  return (u32)f2bf(a) | ((u32)f2bf(b) << 16);
}

// fast GELU (tanh form): validated R6 (absmax unchanged at 0.03125)
__device__ __forceinline__ float gelu_f(float v) {
  float v2 = v * v;
  float wv = v * (2.30220795f + 0.10294322f * v2);
  float ew = __builtin_amdgcn_exp2f(wv);
  return v - v * __builtin_amdgcn_rcpf(ew + 1.0f);
}

#define GLL16(gsrc, ldst)                                                        \
  __builtin_amdgcn_global_load_lds(                                             \
      (const __attribute__((address_space(1))) u32*)(gsrc),                     \
      (__attribute__((address_space(3))) u32*)(ldst), 16, 0, 0)

#define VM(n) asm volatile("s_waitcnt vmcnt(" #n ")" ::: "memory")
#define VM0 asm volatile("s_waitcnt vmcnt(0)" ::: "memory")
#define LGKM0 asm volatile("s_waitcnt lgkmcnt(0)" ::: "memory")
#define RAW_BAR                                                                  \
  do {                                                                           \
    __builtin_amdgcn_s_barrier();                                                \
    asm volatile("" ::: "memory");                                               \
  } while (0)

__device__ __forceinline__ void cvt8(const float* __restrict__ s, u16* __restrict__ d) {
  const float4 f0 = *(const float4*)(s);
  const float4 f1 = *(const float4*)(s + 4);
  uint4 v;
  v.x = pack2(f0.x, f0.y); v.y = pack2(f0.z, f0.w);
  v.z = pack2(f1.x, f1.y); v.w = pack2(f1.z, f1.w);
  *(uint4*)(d) = v;
}

// ---------------- prep: convert x AND w1 to bf16 (one dispatch) ----------------
__global__ __launch_bounds__(256) void k_prep(const float* __restrict__ x,
                                              u16* __restrict__ xb,
                                              const float* __restrict__ w1,
                                              u16* __restrict__ w1b) {
  const int tid = blockIdx.x * 256 + threadIdx.x;   // grid 2048*256
  if (tid < (Mdim * Ddim) / 8) cvt8(x + (size_t)tid * 8, xb + (size_t)tid * 8);
  for (int i = tid; i < NW8; i += 2048 * 256)
    cvt8(w1 + (size_t)i * 8, w1b + (size_t)i * 8);
}

// ---------------- prep2: convert wl AND w2 (one dispatch) ----------------
__global__ __launch_bounds__(256) void k_prep2(const float* __restrict__ wl,
                                               u16* __restrict__ wlb,
                                               const float* __restrict__ w2,
                                               u16* __restrict__ w2b) {
  const int tid = blockIdx.x * 256 + threadIdx.x;
  for (int i = tid; i < NW8; i += 2048 * 256) {
    cvt8(wl + (size_t)i * 8, wlb + (size_t)i * 8);
    cvt8(w2 + (size_t)i * 8, w2b + (size_t)i * 8);
  }
}

// =======================================================================
// 8-phase 256x256 GEMM, R11: A operand loaded GLOBAL->REGISTERS directly
// (per-lane dwordx4 at MFMA fragment addresses; A is L2/L3-hot), B staged
// via GLL16 into XOR-swizzled LDS (cold weight stream). LDS traffic/tile
// drops 256KB -> 96KB (was co-bottleneck with MFMA).
// B LDS: 2 bufs x 16384 u16 (32 KB each) at (buf<<14).
// Register refill ledger (af half refilled 2 phases before first use,
// immediately after its last read):
//   p0: loadA(T,h1) + rdB(h0,h1)  |BAR LGKM0| q(0,0) |BAR|
//   p1: stageB(T+2)               |BAR|       q(0,1) |BAR|
//   p2: loadA(T+1,h0)             |BAR|       q(1,1) |BAR|
//   p3: VM(28)                    |BAR|       q(1,0) |BAR|
// vmcnt ledger: after B(T+1): Ah0(T)8 + Ah1(T)8 + B(T+2)4 + Ah0(T+1)8 = 28.
// Prologue: B(0)4,B(1)4,Ah0(0)8 -> VM(12). NT-2: VM(24) (no B stage).
// =======================================================================
template <int NT>
__device__ __forceinline__ void gemm8r(const u16* __restrict__ A0_,
                                       const u16* __restrict__ A1_,
                                       const u16* __restrict__ B0,
                                       const u16* __restrict__ B1,
                                       u16* lds, f32x4 (&acc)[8][4], const int t) {
  const int w = t >> 6, l = t & 63;
  const int wr = (w >> 2) << 7;       // 0 / 128
  const int wc = (w & 3) << 6;        // 0..192
  const int lr = l & 15, c4 = l >> 4, r7 = l & 7;
  const int sl0 = ((c4 ^ r7) << 3);
  const int sl1 = (((4 | c4) ^ r7) << 3);
  const size_t soff = (size_t)((w << 5) + (l >> 3)) * Ddim + (((l & 7) ^ (l >> 3)) << 3);

  auto stageB = [&](int tt) {
    const u16* src = (NT == 24 && tt >= 12) ? B1 : B0;
    const int kk = (NT == 24 && tt >= 12) ? tt - 12 : tt;
    u16* d = lds + ((tt & 1) << 14) + (w << 11);
    const u16* s = src + soff + (kk << 6);
#pragma unroll
    for (int i = 0; i < 4; ++i)
      GLL16(s + (size_t)(i << 3) * Ddim, d + (i << 9));
  };
  // A fragment direct from global: af[m*2+ks] = A[wr+half*64+m*16+lr][k: ks*32+c4*8 ..+7]
  auto loadA = [&](int tt, int half, short8 (&af)[8]) {
    const u16* src = (NT == 24 && tt >= 12) ? A1_ : A0_;
    const int kk = (NT == 24 && tt >= 12) ? tt - 12 : tt;
    const u16* base = src + (size_t)(wr + (half << 6) + lr) * Ddim + (kk << 6) + (c4 << 3);
#pragma unroll
    for (int m = 0; m < 4; ++m) {
      af[m * 2]     = *(const short8*)(base + (size_t)(m << 4) * Ddim);
      af[m * 2 + 1] = *(const short8*)(base + (size_t)(m << 4) * Ddim + 32);
    }
  };
  auto rdB = [&](int buf, int half, short8 (&bfh)[4]) {
    const u16* bb = lds + (buf << 14) + (wc + (half << 5) + lr) * 64;
#pragma unroll
    for (int n = 0; n < 2; ++n) {
      bfh[n * 2]     = *(const short8*)(bb + (n << 10) + sl0);
      bfh[n * 2 + 1] = *(const short8*)(bb + (n << 10) + sl1);
    }
  };
  auto q = [&](int mh, int nh, short8 (&af)[8], short8 (&bfh)[4]) {
    __builtin_amdgcn_s_setprio(1);
#pragma unroll
    for (int m = 0; m < 4; ++m)
#pragma unroll
      for (int n = 0; n < 2; ++n) {
        f32x4 c = acc[mh * 4 + m][nh * 2 + n];
        c = __builtin_amdgcn_mfma_f32_16x16x32_bf16(af[m * 2],     bfh[n * 2],     c, 0, 0, 0);
        c = __builtin_amdgcn_mfma_f32_16x16x32_bf16(af[m * 2 + 1], bfh[n * 2 + 1], c, 0, 0, 0);
        acc[mh * 4 + m][nh * 2 + n] = c;
      }
    __builtin_amdgcn_s_setprio(0);
  };

  short8 af0[8], af1[8], bf0[4], bf1[4];

  // prologue: B(0),B(1) staged; Ah0(0) in flight. VM(12): B(0) landed.
  stageB(0); stageB(1);
  loadA(0, 0, af0);
  VM(12);
  RAW_BAR;

#pragma unroll 2
  for (int T = 0; T < NT - 2; ++T) {
    const int buf = T & 1;
    loadA(T, 1, af1);
    rdB(buf, 0, bf0); rdB(buf, 1, bf1);
    RAW_BAR; LGKM0; q(0, 0, af0, bf0); RAW_BAR;   // p0
    stageB(T + 2);
    RAW_BAR; q(0, 1, af0, bf1); RAW_BAR;          // p1
    loadA(T + 1, 0, af0);
    RAW_BAR; q(1, 1, af1, bf1); RAW_BAR;          // p2
    VM(28);                                        // B(T+1) landed
    RAW_BAR; q(1, 0, af1, bf0); RAW_BAR;          // p3
  }
  {  // T = NT-2: no B stage; VM(24) -> B(NT-1) landed
    const int buf = (NT - 2) & 1;
    loadA(NT - 2, 1, af1);
    rdB(buf, 0, bf0); rdB(buf, 1, bf1);
    RAW_BAR; LGKM0; q(0, 0, af0, bf0); RAW_BAR;
    RAW_BAR; q(0, 1, af0, bf1); RAW_BAR;
    loadA(NT - 1, 0, af0);
    RAW_BAR; q(1, 1, af1, bf1); RAW_BAR;
    VM(24);
    RAW_BAR; q(1, 0, af1, bf0); RAW_BAR;
  }
  {  // T = NT-1: pure compute
    const int buf = (NT - 1) & 1;
    loadA(NT - 1, 1, af1);
    rdB(buf, 0, bf0); rdB(buf, 1, bf1);
    RAW_BAR; LGKM0; q(0, 0, af0, bf0); RAW_BAR;
    RAW_BAR; q(0, 1, af0, bf1); RAW_BAR;
    RAW_BAR; q(1, 1, af1, bf1); RAW_BAR;
    q(1, 0, af1, bf0);
  }
}

// =======================================================================
// Epilogue (R6, verified): bias[+gelu] -> bf16 -> wave-private swizzled LDS
// [128][64] -> 16x {ds_read_b128 + global_store_dwordx4}. VM0 first: drain
// any outstanding vmem before LDS reuse.
// =======================================================================
template <bool GELU>
__device__ __forceinline__ void epi_store(f32x4 (&acc)[8][4], const float* bias,
                                          u16* lds, u16* gout, int m_base, int n_base,
                                          const int t) {
  const int w = t >> 6, l = t & 63;
  const int lr = l & 15, c4 = l >> 4;
  u16* reg = lds + (w << 13);

  VM0;
  LGKM0;
  __builtin_amdgcn_sched_barrier(0);
  RAW_BAR;

  float bv[4];
#pragma unroll
  for (int nf = 0; nf < 4; ++nf) bv[nf] = bias[(nf << 4) + lr];

#pragma unroll
  for (int mf = 0; mf < 8; ++mf) {
#pragma unroll
    for (int nf = 0; nf < 4; ++nf) {
      const int slot = (nf << 1) + (lr >> 3);
      const int bis = (lr & 7);
#pragma unroll
      for (int j = 0; j < 4; ++j) {
        float v = acc[mf][nf][j] + bv[nf];
        if (GELU) v = gelu_f(v);
        const int row = (mf << 4) + (c4 << 2) + j;
        reg[row * 64 + ((slot ^ (row & 7)) << 3) + bis] = f2bf(v);
      }
    }
  }
  const int g = l >> 3;
  const int phys = ((l & 7) ^ g) << 3;
#pragma unroll
  for (int r = 0; r < 16; ++r) {
    const int row = (r << 3) + g;
    short8 v = *(const short8*)(reg + row * 64 + phys);
    *(short8*)(gout + (size_t)(m_base + row) * Ddim + n_base + ((l & 7) << 3)) = v;
  }
}

// block decode: 1200 blocks = 100 experts x (4m x 3n); bijective XCD swizzle.
__device__ __forceinline__ void decode8(int bid, int& e, int& m0, int& n0) {
  const int s = (bid & 7) * 150 + (bid >> 3);   // 0..1199
  e = s / 12;
  const int r = s % 12;
  m0 = (r & 3) << 8;
  n0 = (r >> 2) << 8;
}

// ---------------- kernel A: h = gelu(x @ w1^T + b1) ----------------
__global__ __launch_bounds__(512, 2) void k_h11(const u16* __restrict__ xb,
                                                const u16* __restrict__ w1b,
                                                const float* __restrict__ b1,
                                                u16* __restrict__ hout) {
  __shared__ __align__(16) u16 lds[65536];   // 128 KB (B bufs 64 KB + epilogue)
  int e, m0, n0;
  decode8(blockIdx.x, e, m0, n0);
  const int t = threadIdx.x;
  f32x4 acc[8][4] = {};
  gemm8r<12>(xb + (size_t)m0 * Ddim, nullptr,
             w1b + (size_t)e * DD + (size_t)n0 * Ddim, nullptr, lds, acc, t);

  const int w = t >> 6;
  const int wr = (w >> 2) << 7, wc = (w & 3) << 6;
  epi_store<true>(acc, b1 + (size_t)e * Ddim + n0 + wc, lds,
                  hout + (size_t)e * Mdim * Ddim, m0 + wr, n0 + wc, t);
}

// ---------------- kernel B: x@wl^T + h@w2^T + biases -> bf16 tbuf ----------------
__global__ __launch_bounds__(512, 2) void k_out11(const u16* __restrict__ xb,
                                                  const u16* __restrict__ hbuf,
                                                  const u16* __restrict__ wlb,
                                                  const float* __restrict__ b_lin,
                                                  const u16* __restrict__ w2b,
                                                  const float* __restrict__ b2,
                                                  u16* __restrict__ tout) {
  __shared__ __align__(16) u16 lds[65536];   // 128 KB
  int e, m0, n0;
  decode8(blockIdx.x, e, m0, n0);
  const int t = threadIdx.x;
  f32x4 acc[8][4] = {};
  gemm8r<24>(xb + (size_t)m0 * Ddim,
             hbuf + (size_t)e * Mdim * Ddim + (size_t)m0 * Ddim,
             wlb + (size_t)e * DD + (size_t)n0 * Ddim,
             w2b + (size_t)e * DD + (size_t)n0 * Ddim, lds, acc, t);

  const int w = t >> 6, l = t & 63;
  const int wr = (w >> 2) << 7, wc = (w & 3) << 6;
  const int lr = l & 15;
  const float* bm = b2 + (size_t)e * Ddim + n0 + wc;
#pragma unroll
  for (int nf = 0; nf < 4; ++nf) {
    const float bmv = bm[(nf << 4) + lr];
#pragma unroll
    for (int mf = 0; mf < 8; ++mf)
#pragma unroll
      for (int j = 0; j < 4; ++j) acc[mf][nf][j] += bmv;
  }
  epi_store<false>(acc, b_lin + (size_t)e * Ddim + n0 + wc, lds,
                   tout + (size_t)e * Mdim * Ddim, m0 + wr, n0 + wc, t);
}

// ---------------- transpose [E][M*D] -> [M*D][E] (bf16 tbuf) ----------------
__global__ __launch_bounds__(256) void k_tr_bf(const u16* __restrict__ tbuf,
                                               float* __restrict__ out) {
  __shared__ __align__(16) u16 tile[100 * 260];
  const int t = threadIdx.x;
  const size_t MD = (size_t)Mdim * Ddim;
  const size_t md0 = (size_t)blockIdx.x * 256;
#pragma unroll
  for (int p = 0; p < 25; ++p) {
    const int e = p * 4 + (t >> 6);
    const int c = (t & 63) * 4;
    uint2 v = *(const uint2*)(tbuf + (size_t)e * MD + md0 + c);
    *(uint2*)(&tile[e * 260 + c]) = v;
  }
  __syncthreads();
  const size_t obase = md0 * 100;
#pragma unroll 5
  for (int i = 0; i < 100; ++i) {
    const int flat = t + i * 256;                     // < 25600
    const int mo = (int)(((u32)flat * 5243u) >> 19);  // /100
    const int e = flat - mo * 100;
    out[obase + flat] = bf2f(tile[e * 260 + mo]);
  }
}

// =======================================================================
// Legacy fallback (tiny workspace): 2-barrier loop, f32 weights reg-staged,
// direct strided writes, chunked over experts. Slow but correct.
// =======================================================================
__global__ void k_cvt(const float* __restrict__ x, u16* __restrict__ xb) {
  size_t i = ((size_t)blockIdx.x * 256 + threadIdx.x) * 4;
  float4 v = *(const float4*)(x + i);
  uint2 r;
  r.x = pack2(v.x, v.y);
  r.y = pack2(v.z, v.w);
  *(uint2*)(xb + i) = r;
}

__device__ __forceinline__ void gemm_phase_f32(const u16* __restrict__ Ag,
                                               const float* __restrict__ Wg,
                                               u16* As, u16* Bs, f32x4 (&acc)[4][4], int t) {
  const int w = t >> 6, l = t & 63;
  const int lrow = l & 15, lk = (l >> 4) << 3;
  const int wr = ((w >> 1) << 6), wc = ((w & 1) << 6);
  for (int kt = 0; kt < Ddim; kt += 32) {
#pragma unroll
    for (int i = 0; i < 2; ++i) {
      GLL16(Ag + (size_t)((w << 5) + (i << 4) + (l >> 2)) * Ddim + kt + ((l & 3) << 3),
            As + (((w << 5) + (i << 4)) << 5));
    }
    {
      const int r = t >> 1, c = (t & 1) << 4;
      const float* src = Wg + (size_t)r * Ddim + kt + c;
      const float4 f0 = *(const float4*)(src);
      const float4 f1 = *(const float4*)(src + 4);
      const float4 f2 = *(const float4*)(src + 8);
      const float4 f3 = *(const float4*)(src + 12);
      uint4 v0, v1;
      v0.x = pack2(f0.x, f0.y); v0.y = pack2(f0.z, f0.w);
      v0.z = pack2(f1.x, f1.y); v0.w = pack2(f1.z, f1.w);
      v1.x = pack2(f2.x, f2.y); v1.y = pack2(f2.z, f2.w);
      v1.z = pack2(f3.x, f3.y); v1.w = pack2(f3.z, f3.w);
      *(uint4*)(&Bs[r * 32 + c]) = v0;
      *(uint4*)(&Bs[r * 32 + c + 8]) = v1;
    }
    __syncthreads();
    short8 af[4], bfr[4];
#pragma unroll
    for (int f = 0; f < 4; ++f) {
      af[f]  = *(const short8*)(&As[(wr + f * 16 + lrow) * 32 + lk]);
      bfr[f] = *(const short8*)(&Bs[(wc + f * 16 + lrow) * 32 + lk]);
    }
#pragma unroll
    for (int fm = 0; fm < 4; ++fm)
#pragma unroll
      for (int fn = 0; fn < 4; ++fn)
        acc[fm][fn] = __builtin_amdgcn_mfma_f32_16x16x32_bf16(af[fm], bfr[fn], acc[fm][fn], 0, 0, 0);
    __syncthreads();
  }
}

__global__ __launch_bounds__(256) void k_h2(const u16* __restrict__ xb,
                                            const float* __restrict__ w1,
                                            const float* __restrict__ b1,
                                            u16* __restrict__ hout, int e_base) {
  __shared__ __align__(16) u16 As[128 * 32];
  __shared__ __align__(16) u16 Bs[128 * 32];
  const int el = blockIdx.x / 48, r = blockIdx.x % 48;
  const int m0 = (r / 6) * 128, n0 = (r % 6) * 128;
  const int e = e_base + el;
  const int t = threadIdx.x, l = t & 63, wv = t >> 6;
  const int wr = (wv >> 1) * 64, wc = (wv & 1) * 64, lrow = l & 15;
  f32x4 acc[4][4] = {};
  gemm_phase_f32(xb + (size_t)m0 * Ddim, w1 + (size_t)e * DD + (size_t)n0 * Ddim, As, Bs, acc, t);
  const float* bias = b1 + (size_t)e * Ddim + n0;
  u16* hb = hout + (size_t)el * Mdim * Ddim;
#pragma unroll
  for (int fm = 0; fm < 4; ++fm) {
    const int mb = m0 + wr + fm * 16 + ((l >> 4) << 2);
#pragma unroll
    for (int fn = 0; fn < 4; ++fn) {
      const int nc = wc + fn * 16 + lrow;
      const float bv = bias[nc];
#pragma unroll
      for (int j = 0; j < 4; ++j) {
        float v = acc[fm][fn][j] + bv;
        v = 0.5f * v * (1.0f + erff(v * 0.7071067811865475f));
        hb[(size_t)(mb + j) * Ddim + n0 + nc] = f2bf(v);
      }
    }
  }
}

__global__ __launch_bounds__(256) void k_out2(
    const u16* __restrict__ xb, const u16* __restrict__ hbuf,
    const float* __restrict__ wl, const float* __restrict__ b_lin,
    const float* __restrict__ w2, const float* __restrict__ b2,
    float* __restrict__ out, int e_base) {
  __shared__ __align__(16) u16 As[128 * 32];
  __shared__ __align__(16) u16 Bs[128 * 32];
  const int el = blockIdx.x / 48, r = blockIdx.x % 48;
  const int m0 = (r / 6) * 128, n0 = (r % 6) * 128;
  const int e = e_base + el;
  const int t = threadIdx.x, l = t & 63, wv = t >> 6;
  const int wr = (wv >> 1) * 64, wc = (wv & 1) * 64, lrow = l & 15;
  f32x4 acc[4][4] = {};
  gemm_phase_f32(xb + (size_t)m0 * Ddim, wl + (size_t)e * DD + (size_t)n0 * Ddim, As, Bs, acc, t);
  gemm_phase_f32(hbuf + (size_t)el * Mdim * Ddim + (size_t)m0 * Ddim,
                 w2 + (size_t)e * DD + (size_t)n0 * Ddim, As, Bs, acc, t);
  const float* bl = b_lin + (size_t)e * Ddim + n0;
  const float* bm = b2 + (size_t)e * Ddim + n0;
#pragma unroll
  for (int fm = 0; fm < 4; ++fm) {
    const int mb = m0 + wr + fm * 16 + ((l >> 4) << 2);
#pragma unroll
    for (int fn = 0; fn < 4; ++fn) {
      const int nc = wc + fn * 16 + lrow;
      const float bv = bl[nc] + bm[nc];
#pragma unroll
      for (int j = 0; j < 4; ++j)
        out[((size_t)(mb + j) * Ddim + n0 + nc) * Edim + e] = acc[fm][fn][j] + bv;
    }
  }
}

extern "C" void kernel_launch(void* const* d_in, const int* in_sizes, int n_in,
                              void* d_out, int out_size, void* d_ws, size_t ws_size,
                              hipStream_t stream) {
  const float* x     = (const float*)d_in[0];
  const float* w_lin = (const float*)d_in[1];
  const float* b_lin = (const float*)d_in[2];
  const float* w1    = (const float*)d_in[3];
  const float* b1    = (const float*)d_in[4];
  const float* w2    = (const float*)d_in[5];
  const float* b2    = (const float*)d_in[6];
  float* out = (float*)d_out;

  const size_t MD = (size_t)Mdim * Ddim;          // 786432
  const size_t xb_b = MD * 2;                     // 1.57 MB
  const size_t w_b  = (size_t)Edim * DD * 2;      // 118 MB (one bf16 matrix)
  const size_t h_b  = (size_t)Edim * MD * 2;      // 157 MB
  const size_t tb_b = h_b;                        // 157 MB

  char* base = (char*)d_ws;

  if (ws_size >= xb_b + 3 * w_b + h_b + tb_b) {
    // Preferred (670 MB): prep(x,w1) -> k_h11 -> prep2(wl,w2) -> k_out11 -> tr
    u16* xb   = (u16*)base;
    u16* w1b  = (u16*)(base + xb_b);
    u16* wlb  = (u16*)(base + xb_b + w_b);
    u16* w2b  = (u16*)(base + xb_b + 2 * w_b);
    u16* hbuf = (u16*)(base + xb_b + 3 * w_b);
    u16* tbuf = (u16*)(base + xb_b + 3 * w_b + h_b);
    k_prep<<<dim3(2048), dim3(256), 0, stream>>>(x, xb, w1, w1b);
    k_h11<<<dim3(1200), dim3(512), 0, stream>>>(xb, w1b, b1, hbuf);
    k_prep2<<<dim3(2048), dim3(256), 0, stream>>>(w_lin, wlb, w2, w2b);
    k_out11<<<dim3(1200), dim3(512), 0, stream>>>(xb, hbuf, wlb, b_lin, w2b, b2, tbuf);
    k_tr_bf<<<dim3((u32)(MD / 256)), dim3(256), 0, stream>>>(tbuf, out);
  } else {
    // Chunked fallback: direct strided writes (slow but correct)
    u16* xb = (u16*)base;
    k_cvt<<<dim3((u32)(MD / 1024)), dim3(256), 0, stream>>>(x, xb);
    size_t avail = ws_size > xb_b ? ws_size - xb_b : 0;
    int EC = (int)(avail / (MD * 2));
    if (EC < 1) EC = 1;
    if (EC > Edim) EC = Edim;
    u16* hbuf = (u16*)(base + xb_b);
    for (int e0 = 0; e0 < Edim; e0 += EC) {
      int ne = (Edim - e0) < EC ? (Edim - e0) : EC;
      k_h2<<<dim3(ne * 48), dim3(256), 0, stream>>>(xb, w1, b1, hbuf, e0);
      k_out2<<<dim3(ne * 48), dim3(256), 0, stream>>>(xb, hbuf, w_lin, b_lin, w2, b2,
                                                      out, e0);
    }
  }
}

// Round 12
// 649.676 us; speedup vs baseline: 1.9213x; 1.9213x over previous
//
#include <hip/hip_runtime.h>
#include <hip/hip_bf16.h>
#include <cstdint>

typedef __attribute__((ext_vector_type(8))) short short8;
typedef __attribute__((ext_vector_type(4))) float f32x4;
typedef unsigned short u16;
typedef unsigned int u32;

#define Mdim 1024
#define Ddim 768
#define Edim 100
#define DD (Ddim * Ddim)

__device__ __forceinline__ u16 f2bf(float f) {
  u32 u = __builtin_bit_cast(u32, f);
  u += 0x7fffu + ((u >> 16) & 1u);   // RNE
  return (u16)(u >> 16);
}
__device__ __forceinline__ float bf2f(u16 h) {
  return __builtin_bit_cast(float, ((u32)h) << 16);
}
__device__ __forceinline__ u32 pack2(float a, float b) {
  return (u32)f2bf(a) | ((u32)f2bf(b) << 16);
}
__device__ __forceinline__ float bcf(u32 u) { return __builtin_bit_cast(float, u); }

// fast GELU (tanh form): validated R6 (absmax unchanged at 0.03125)
__device__ __forceinline__ float gelu_f(float v) {
  float v2 = v * v;
  float wv = v * (2.30220795f + 0.10294322f * v2);
  float ew = __builtin_amdgcn_exp2f(wv);
  return v - v * __builtin_amdgcn_rcpf(ew + 1.0f);
}

#define GLL16(gsrc, ldst)                                                        \
  __builtin_amdgcn_global_load_lds(                                             \
      (const __attribute__((address_space(1))) u32*)(gsrc),                     \
      (__attribute__((address_space(3))) u32*)(ldst), 16, 0, 0)

#define VM6 asm volatile("s_waitcnt vmcnt(6)" ::: "memory")
#define VM0 asm volatile("s_waitcnt vmcnt(0)" ::: "memory")
#define LGKM0 asm volatile("s_waitcnt lgkmcnt(0)" ::: "memory")
#define RAW_BAR                                                                  \
  do {                                                                           \
    __builtin_amdgcn_s_barrier();                                                \
    asm volatile("" ::: "memory");                                               \
  } while (0)

// ---------------- x: f32 -> bf16 (1.5 MB, ~5us) ----------------
__global__ void k_cvt(const float* __restrict__ x, u16* __restrict__ xb) {
  size_t i = ((size_t)blockIdx.x * 256 + threadIdx.x) * 4;
  float4 v = *(const float4*)(x + i);
  uint2 r;
  r.x = pack2(v.x, v.y);
  r.y = pack2(v.z, v.w);
  *(uint2*)(xb + i) = r;
}

// =======================================================================
// R12 GEMM core: 256x256 tile, BK=32, 8 waves (2m x 4n), wave tile 128x64.
// A: bf16, GLL16 into LDS, super-row swizzle (2 rows = 128B = 8 slots;
//    logical slot = (row&1)*4 + k16; phys = logical ^ ((row>>1)&7)).
// B: *** f32 weights GLL16'd DIRECTLY *** (no converter pass); LDS B-f32
//    row = 128B = 8 slots, phys = (k>>2) ^ (row&7); converted f32->bf16
//    (RNE pack2) on the LDS->register read path.
// LDS: 2 bufs x (A 16KB + B 32KB) = 96KB (buf b at b*24576 u16).
// One super-phase per tile, 2 barriers:
//   reads(8 A + 8 B ds_read_b128) ; LGKM0 ; BAR    <- all reads of buf done
//   stage(T+2) [2 A + 4 B GLL16]                   <- overwrites buf, safe
//   32 MFMA ; VM6 (T+1 landed, T+2 in flight) ; BAR
// =======================================================================
template <int NT, int SPLIT>
__device__ __forceinline__ void gemm2f(const u16* __restrict__ A0,
                                       const u16* __restrict__ A1,
                                       const float* __restrict__ B0,
                                       const float* __restrict__ B1,
                                       u16* lds, f32x4 (&acc)[8][4], const int t) {
  const int w = t >> 6, l = t & 63;
  const int wr = (w >> 2) << 7;       // 0 / 128
  const int wc = (w & 3) << 6;        // 0..192
  const int lr = l & 15, c4 = l >> 4;

  // --- A read constants (u16 units) ---
  const int aphys = (((lr & 1) << 2) | c4) ^ ((lr >> 1) & 7);
  const int ard = wr * 32 + ((lr >> 1) << 6) + (aphys << 3);   // + mf*512 + buf*24576
  // --- B read constants (u32 units) ---
  const int bp0 = ((c4 << 1)) ^ (lr & 7);
  const int bp1 = ((c4 << 1) | 1) ^ (lr & 7);
  const int brd = (wc + lr) * 32;                               // + nf*512 + p*4
  // --- stage constants ---
  const int alog = (l & 7) ^ ((l >> 3) & 7);
  const size_t agsrc = (size_t)((w << 5) + ((l >> 3) << 1) + (alog >> 2)) * Ddim + ((alog & 3) << 3);
  const size_t bgsrc0 = (size_t)((w << 5) + (l >> 3)) * Ddim + (alog << 2);   // f32 elems, +i*8*Ddim

  auto stage = [&](int tt) {
    const u16* Asrc = (tt >= SPLIT) ? A1 : A0;
    const float* Bsrc = (tt >= SPLIT) ? B1 : B0;
    const int kk = (tt >= SPLIT) ? tt - SPLIT : tt;
    const int buf = tt & 1;
    // A: 2 GLL16 (1KB each)
    u16* ad = lds + buf * 24576 + (w << 10);
    const u16* as = Asrc + agsrc + (kk << 5);
#pragma unroll
    for (int i = 0; i < 2; ++i)
      GLL16(as + (size_t)(i << 4) * Ddim, ad + (i << 9));
    // B: 4 GLL16 (1KB each), f32
    u16* bd = lds + buf * 24576 + 8192 + (w << 11);
    const float* bs = Bsrc + bgsrc0 + (kk << 5);
#pragma unroll
    for (int i = 0; i < 4; ++i)
      GLL16(bs + (size_t)(i << 3) * Ddim, bd + (i << 9));
  };

  short8 af[8], bf[4];
  auto rdA = [&](int buf) {
    const u16* ab = lds + buf * 24576 + ard;
#pragma unroll
    for (int mf = 0; mf < 8; ++mf) af[mf] = *(const short8*)(ab + (mf << 9));
  };
  auto rdB = [&](int buf) {
    const u32* bb = (const u32*)(lds) + buf * 12288 + 4096 + brd;
#pragma unroll
    for (int nf = 0; nf < 4; ++nf) {
      const uint4 q0 = *(const uint4*)(bb + (nf << 9) + (bp0 << 2));
      const uint4 q1 = *(const uint4*)(bb + (nf << 9) + (bp1 << 2));
      uint4 o;
      o.x = pack2(bcf(q0.x), bcf(q0.y));
      o.y = pack2(bcf(q0.z), bcf(q0.w));
      o.z = pack2(bcf(q1.x), bcf(q1.y));
      o.w = pack2(bcf(q1.z), bcf(q1.w));
      bf[nf] = __builtin_bit_cast(short8, o);
    }
  };
  auto qall = [&]() {
    __builtin_amdgcn_s_setprio(1);
#pragma unroll
    for (int mf = 0; mf < 8; ++mf)
#pragma unroll
      for (int nf = 0; nf < 4; ++nf)
        acc[mf][nf] = __builtin_amdgcn_mfma_f32_16x16x32_bf16(af[mf], bf[nf], acc[mf][nf], 0, 0, 0);
    __builtin_amdgcn_s_setprio(0);
  };

  // prologue: tiles 0,1 staged; VM6 -> tile 0 landed (tile 1 may fly)
  stage(0); stage(1);
  VM6;
  RAW_BAR;

#pragma unroll 2
  for (int T = 0; T < NT - 2; ++T) {
    const int buf = T & 1;
    rdA(buf); rdB(buf);
    LGKM0;                 // this wave's reads of buf complete
    RAW_BAR;               // ALL waves' reads complete -> buf overwritable
    stage(T + 2);          // issue early: max latency cover
    qall();
    VM6;                   // tile T+1 fully landed; T+2's 6 stay in flight
    RAW_BAR;
  }
  {  // T = NT-2: no stage; drain so tile NT-1 ready
    const int buf = (NT - 2) & 1;
    rdA(buf); rdB(buf);
    LGKM0;
    RAW_BAR;
    qall();
    VM0;
    RAW_BAR;
  }
  {  // T = NT-1: pure compute
    const int buf = (NT - 1) & 1;
    rdA(buf); rdB(buf);
    qall();
  }
}

// =======================================================================
// Epilogue (two-pass, VGPR-safe; logic verified in R9 which passed absmax):
// wave-private 8KB LDS [64][64] slot-XOR tile; per pass write 64 rows ->
// 8x {ds_read_b128 + global_store_dwordx4}. 8 waves x 8KB = 64KB <= 96KB.
// =======================================================================
template <bool GELU>
__device__ __forceinline__ void epi32(f32x4 (&acc)[8][4], const float* bias,
                                      u16* lds, u16* gout, int m_base, int n_base,
                                      const int t) {
  const int w = t >> 6, l = t & 63;
  const int lr = l & 15, c4 = l >> 4;
  u16* reg = lds + (w << 12);   // 4096 u16 = 8 KB per wave

  VM0;
  LGKM0;
  __builtin_amdgcn_sched_barrier(0);
  RAW_BAR;

  float bv[4];
#pragma unroll
  for (int nf = 0; nf < 4; ++nf) bv[nf] = bias[(nf << 4) + lr];

  const int g = l >> 3;
  const int phys = ((l & 7) ^ g) << 3;

#pragma unroll
  for (int pass = 0; pass < 2; ++pass) {
#pragma unroll
    for (int mf = 0; mf < 4; ++mf) {
      const int MF = pass * 4 + mf;
#pragma unroll
      for (int nf = 0; nf < 4; ++nf) {
        const int slot = (nf << 1) + (lr >> 3);
        const int bis = (lr & 7);
#pragma unroll
        for (int j = 0; j < 4; ++j) {
          float v = acc[MF][nf][j] + bv[nf];
          if (GELU) v = gelu_f(v);
          const int row = (mf << 4) + (c4 << 2) + j;   // 0..63
          reg[row * 64 + ((slot ^ (row & 7)) << 3) + bis] = f2bf(v);
        }
      }
    }
    LGKM0;
#pragma unroll
    for (int r = 0; r < 8; ++r) {
      const int row = (r << 3) + g;
      short8 v = *(const short8*)(reg + row * 64 + phys);
      *(short8*)(gout + (size_t)(m_base + pass * 64 + row) * Ddim + n_base + ((l & 7) << 3)) = v;
    }
    LGKM0;   // reads retired before next pass overwrites (WAR)
  }
}

// block decode: 1200 blocks = 100 experts x (4m x 3n); bijective XCD swizzle.
__device__ __forceinline__ void decode8(int bid, int& e, int& m0, int& n0) {
  const int s = (bid & 7) * 150 + (bid >> 3);   // 0..1199
  e = s / 12;
  const int r = s % 12;
  m0 = (r & 3) << 8;
  n0 = (r >> 2) << 8;
}

// ---------------- kernel A: h = gelu(x @ w1^T + b1), w1 f32 direct ----------------
__global__ __launch_bounds__(512, 2) void k_h12(const u16* __restrict__ xb,
                                                const float* __restrict__ w1,
                                                const float* __restrict__ b1,
                                                u16* __restrict__ hout) {
  __shared__ __align__(16) u16 lds[49152];   // 96 KB
  int e, m0, n0;
  decode8(blockIdx.x, e, m0, n0);
  const int t = threadIdx.x;
  f32x4 acc[8][4] = {};
  gemm2f<24, 24>(xb + (size_t)m0 * Ddim, nullptr,
                 w1 + (size_t)e * DD + (size_t)n0 * Ddim, nullptr, lds, acc, t);

  const int w = t >> 6;
  const int wr = (w >> 2) << 7, wc = (w & 3) << 6;
  epi32<true>(acc, b1 + (size_t)e * Ddim + n0 + wc, lds,
              hout + (size_t)e * Mdim * Ddim, m0 + wr, n0 + wc, t);
}

// ---------------- kernel B: x@wl^T + h@w2^T + biases -> bf16 tbuf ----------------
__global__ __launch_bounds__(512, 2) void k_out12(const u16* __restrict__ xb,
                                                  const u16* __restrict__ hbuf,
                                                  const float* __restrict__ wl,
                                                  const float* __restrict__ b_lin,
                                                  const float* __restrict__ w2,
                                                  const float* __restrict__ b2,
                                                  u16* __restrict__ tout) {
  __shared__ __align__(16) u16 lds[49152];   // 96 KB
  int e, m0, n0;
  decode8(blockIdx.x, e, m0, n0);
  const int t = threadIdx.x;
  f32x4 acc[8][4] = {};
  gemm2f<48, 24>(xb + (size_t)m0 * Ddim,
                 hbuf + (size_t)e * Mdim * Ddim + (size_t)m0 * Ddim,
                 wl + (size_t)e * DD + (size_t)n0 * Ddim,
                 w2 + (size_t)e * DD + (size_t)n0 * Ddim, lds, acc, t);

  const int w = t >> 6, l = t & 63;
  const int wr = (w >> 2) << 7, wc = (w & 3) << 6;
  const int lr = l & 15;
  const float* bm = b2 + (size_t)e * Ddim + n0 + wc;
#pragma unroll
  for (int nf = 0; nf < 4; ++nf) {
    const float bmv = bm[(nf << 4) + lr];
#pragma unroll
    for (int mf = 0; mf < 8; ++mf)
#pragma unroll
      for (int j = 0; j < 4; ++j) acc[mf][nf][j] += bmv;
  }
  epi32<false>(acc, b_lin + (size_t)e * Ddim + n0 + wc, lds,
               tout + (size_t)e * Mdim * Ddim, m0 + wr, n0 + wc, t);
}

// ---------------- transpose [E][M*D] -> [M*D][E] (bf16 tbuf) ----------------
__global__ __launch_bounds__(256) void k_tr_bf(const u16* __restrict__ tbuf,
                                               float* __restrict__ out) {
  __shared__ __align__(16) u16 tile[100 * 260];
  const int t = threadIdx.x;
  const size_t MD = (size_t)Mdim * Ddim;
  const size_t md0 = (size_t)blockIdx.x * 256;
#pragma unroll
  for (int p = 0; p < 25; ++p) {
    const int e = p * 4 + (t >> 6);
    const int c = (t & 63) * 4;
    uint2 v = *(const uint2*)(tbuf + (size_t)e * MD + md0 + c);
    *(uint2*)(&tile[e * 260 + c]) = v;
  }
  __syncthreads();
  const size_t obase = md0 * 100;
#pragma unroll 5
  for (int i = 0; i < 100; ++i) {
    const int flat = t + i * 256;                     // < 25600
    const int mo = (int)(((u32)flat * 5243u) >> 19);  // /100
    const int e = flat - mo * 100;
    out[obase + flat] = bf2f(tile[e * 260 + mo]);
  }
}

// =======================================================================
// Legacy fallback (tiny workspace): 2-barrier loop, f32 weights reg-staged,
// direct strided writes, chunked over experts. Slow but correct.
// =======================================================================
__device__ __forceinline__ void gemm_phase_f32(const u16* __restrict__ Ag,
                                               const float* __restrict__ Wg,
                                               u16* As, u16* Bs, f32x4 (&acc)[4][4], int t) {
  const int w = t >> 6, l = t & 63;
  const int lrow = l & 15, lk = (l >> 4) << 3;
  const int wr = ((w >> 1) << 6), wc = ((w & 1) << 6);
  for (int kt = 0; kt < Ddim; kt += 32) {
#pragma unroll
    for (int i = 0; i < 2; ++i) {
      GLL16(Ag + (size_t)((w << 5) + (i << 4) + (l >> 2)) * Ddim + kt + ((l & 3) << 3),
            As + (((w << 5) + (i << 4)) << 5));
    }
    {
      const int r = t >> 1, c = (t & 1) << 4;
      const float* src = Wg + (size_t)r * Ddim + kt + c;
      const float4 f0 = *(const float4*)(src);
      const float4 f1 = *(const float4*)(src + 4);
      const float4 f2 = *(const float4*)(src + 8);
      const float4 f3 = *(const float4*)(src + 12);
      uint4 v0, v1;
      v0.x = pack2(f0.x, f0.y); v0.y = pack2(f0.z, f0.w);
      v0.z = pack2(f1.x, f1.y); v0.w = pack2(f1.z, f1.w);
      v1.x = pack2(f2.x, f2.y); v1.y = pack2(f2.z, f2.w);
      v1.z = pack2(f3.x, f3.y); v1.w = pack2(f3.z, f3.w);
      *(uint4*)(&Bs[r * 32 + c]) = v0;
      *(uint4*)(&Bs[r * 32 + c + 8]) = v1;
    }
    __syncthreads();
    short8 af[4], bfr[4];
#pragma unroll
    for (int f = 0; f < 4; ++f) {
      af[f]  = *(const short8*)(&As[(wr + f * 16 + lrow) * 32 + lk]);
      bfr[f] = *(const short8*)(&Bs[(wc + f * 16 + lrow) * 32 + lk]);
    }
#pragma unroll
    for (int fm = 0; fm < 4; ++fm)
#pragma unroll
      for (int fn = 0; fn < 4; ++fn)
        acc[fm][fn] = __builtin_amdgcn_mfma_f32_16x16x32_bf16(af[fm], bfr[fn], acc[fm][fn], 0, 0, 0);
    __syncthreads();
  }
}

__global__ __launch_bounds__(256) void k_h2(const u16* __restrict__ xb,
                                            const float* __restrict__ w1,
                                            const float* __restrict__ b1,
                                            u16* __restrict__ hout, int e_base) {
  __shared__ __align__(16) u16 As[128 * 32];
  __shared__ __align__(16) u16 Bs[128 * 32];
  const int el = blockIdx.x / 48, r = blockIdx.x % 48;
  const int m0 = (r / 6) * 128, n0 = (r % 6) * 128;
  const int e = e_base + el;
  const int t = threadIdx.x, l = t & 63, wv = t >> 6;
  const int wr = (wv >> 1) * 64, wc = (wv & 1) * 64, lrow = l & 15;
  f32x4 acc[4][4] = {};
  gemm_phase_f32(xb + (size_t)m0 * Ddim, w1 + (size_t)e * DD + (size_t)n0 * Ddim, As, Bs, acc, t);
  const float* bias = b1 + (size_t)e * Ddim + n0;
  u16* hb = hout + (size_t)el * Mdim * Ddim;
#pragma unroll
  for (int fm = 0; fm < 4; ++fm) {
    const int mb = m0 + wr + fm * 16 + ((l >> 4) << 2);
#pragma unroll
    for (int fn = 0; fn < 4; ++fn) {
      const int nc = wc + fn * 16 + lrow;
      const float bv = bias[nc];
#pragma unroll
      for (int j = 0; j < 4; ++j) {
        float v = acc[fm][fn][j] + bv;
        v = 0.5f * v * (1.0f + erff(v * 0.7071067811865475f));
        hb[(size_t)(mb + j) * Ddim + n0 + nc] = f2bf(v);
      }
    }
  }
}

__global__ __launch_bounds__(256) void k_out2(
    const u16* __restrict__ xb, const u16* __restrict__ hbuf,
    const float* __restrict__ wl, const float* __restrict__ b_lin,
    const float* __restrict__ w2, const float* __restrict__ b2,
    float* __restrict__ out, int e_base) {
  __shared__ __align__(16) u16 As[128 * 32];
  __shared__ __align__(16) u16 Bs[128 * 32];
  const int el = blockIdx.x / 48, r = blockIdx.x % 48;
  const int m0 = (r / 6) * 128, n0 = (r % 6) * 128;
  const int e = e_base + el;
  const int t = threadIdx.x, l = t & 63, wv = t >> 6;
  const int wr = (wv >> 1) * 64, wc = (wv & 1) * 64, lrow = l & 15;
  f32x4 acc[4][4] = {};
  gemm_phase_f32(xb + (size_t)m0 * Ddim, wl + (size_t)e * DD + (size_t)n0 * Ddim, As, Bs, acc, t);
  gemm_phase_f32(hbuf + (size_t)el * Mdim * Ddim + (size_t)m0 * Ddim,
                 w2 + (size_t)e * DD + (size_t)n0 * Ddim, As, Bs, acc, t);
  const float* bl = b_lin + (size_t)e * Ddim + n0;
  const float* bm = b2 + (size_t)e * Ddim + n0;
#pragma unroll
  for (int fm = 0; fm < 4; ++fm) {
    const int mb = m0 + wr + fm * 16 + ((l >> 4) << 2);
#pragma unroll
    for (int fn = 0; fn < 4; ++fn) {
      const int nc = wc + fn * 16 + lrow;
      const float bv = bl[nc] + bm[nc];
#pragma unroll
      for (int j = 0; j < 4; ++j)
        out[((size_t)(mb + j) * Ddim + n0 + nc) * Edim + e] = acc[fm][fn][j] + bv;
    }
  }
}

extern "C" void kernel_launch(void* const* d_in, const int* in_sizes, int n_in,
                              void* d_out, int out_size, void* d_ws, size_t ws_size,
                              hipStream_t stream) {
  const float* x     = (const float*)d_in[0];
  const float* w_lin = (const float*)d_in[1];
  const float* b_lin = (const float*)d_in[2];
  const float* w1    = (const float*)d_in[3];
  const float* b1    = (const float*)d_in[4];
  const float* w2    = (const float*)d_in[5];
  const float* b2    = (const float*)d_in[6];
  float* out = (float*)d_out;

  const size_t MD = (size_t)Mdim * Ddim;          // 786432
  const size_t xb_b = MD * 2;                     // 1.57 MB
  const size_t h_b  = (size_t)Edim * MD * 2;      // 157 MB
  const size_t tb_b = h_b;                        // 157 MB

  char* base = (char*)d_ws;
  u16* xb = (u16*)base;
  k_cvt<<<dim3((u32)(MD / 1024)), dim3(256), 0, stream>>>(x, xb);

  if (ws_size >= xb_b + h_b + tb_b) {
    // Preferred (316 MB): f32-weight-direct GEMMs (no converter passes)
    u16* hbuf = (u16*)(base + xb_b);
    u16* tbuf = (u16*)(base + xb_b + h_b);
    k_h12<<<dim3(1200), dim3(512), 0, stream>>>(xb, w1, b1, hbuf);
    k_out12<<<dim3(1200), dim3(512), 0, stream>>>(xb, hbuf, w_lin, b_lin, w2, b2, tbuf);
    k_tr_bf<<<dim3((u32)(MD / 256)), dim3(256), 0, stream>>>(tbuf, out);
  } else {
    // Chunked fallback: direct strided writes (slow but correct)
    size_t avail = ws_size > xb_b ? ws_size - xb_b : 0;
    int EC = (int)(avail / (MD * 2));
    if (EC < 1) EC = 1;
    if (EC > Edim) EC = Edim;
    u16* hbuf = (u16*)(base + xb_b);
    for (int e0 = 0; e0 < Edim; e0 += EC) {
      int ne = (Edim - e0) < EC ? (Edim - e0) : EC;
      k_h2<<<dim3(ne * 48), dim3(256), 0, stream>>>(xb, w1, b1, hbuf, e0);
      k_out2<<<dim3(ne * 48), dim3(256), 0, stream>>>(xb, hbuf, w_lin, b_lin, w2, b2,
                                                      out, e0);
    }
  }
}

// Round 13
// 613.809 us; speedup vs baseline: 2.0336x; 1.0584x over previous
//
#include <hip/hip_runtime.h>
#include <hip/hip_bf16.h>
#include <cstdint>

typedef __attribute__((ext_vector_type(8))) short short8;
typedef __attribute__((ext_vector_type(4))) float f32x4;
typedef unsigned short u16;
typedef unsigned int u32;

#define Mdim 1024
#define Ddim 768
#define Edim 100
#define DD (Ddim * Ddim)

__device__ __forceinline__ u16 f2bf(float f) {
  u32 u = __builtin_bit_cast(u32, f);
  u += 0x7fffu + ((u >> 16) & 1u);   // RNE
  return (u16)(u >> 16);
}
__device__ __forceinline__ float bf2f(u16 h) {
  return __builtin_bit_cast(float, ((u32)h) << 16);
}
__device__ __forceinline__ u32 pack2(float a, float b) {
  return (u32)f2bf(a) | ((u32)f2bf(b) << 16);
}
// HW packed f32->bf16 (RNE), one VALU op for two values
__device__ __forceinline__ u32 cvtpk(float lo, float hi) {
  u32 r;
  asm("v_cvt_pk_bf16_f32 %0, %1, %2" : "=v"(r) : "v"(lo), "v"(hi));
  return r;
}
__device__ __forceinline__ u32 cvtpk_u(u32 lo, u32 hi) {   // inputs are f32 bit patterns
  u32 r;
  asm("v_cvt_pk_bf16_f32 %0, %1, %2" : "=v"(r) : "v"(lo), "v"(hi));
  return r;
}

// fast GELU (tanh form): validated R6 (absmax unchanged at 0.03125)
__device__ __forceinline__ float gelu_f(float v) {
  float v2 = v * v;
  float wv = v * (2.30220795f + 0.10294322f * v2);
  float ew = __builtin_amdgcn_exp2f(wv);
  return v - v * __builtin_amdgcn_rcpf(ew + 1.0f);
}

#define GLL16(gsrc, ldst)                                                        \
  __builtin_amdgcn_global_load_lds(                                             \
      (const __attribute__((address_space(1))) u32*)(gsrc),                     \
      (__attribute__((address_space(3))) u32*)(ldst), 16, 0, 0)

#define VM6 asm volatile("s_waitcnt vmcnt(6)" ::: "memory")
#define VM0 asm volatile("s_waitcnt vmcnt(0)" ::: "memory")
#define LGKM0 asm volatile("s_waitcnt lgkmcnt(0)" ::: "memory")
#define RAW_BAR                                                                  \
  do {                                                                           \
    __builtin_amdgcn_s_barrier();                                                \
    asm volatile("" ::: "memory");                                               \
  } while (0)

// ---------------- x: f32 -> bf16 (1.5 MB, ~5us) ----------------
__global__ void k_cvt(const float* __restrict__ x, u16* __restrict__ xb) {
  size_t i = ((size_t)blockIdx.x * 256 + threadIdx.x) * 4;
  float4 v = *(const float4*)(x + i);
  uint2 r;
  r.x = cvtpk(v.x, v.y);
  r.y = cvtpk(v.z, v.w);
  *(uint2*)(xb + i) = r;
}

// =======================================================================
// R13 GEMM core (R12 structure, verified 650us/absmax 0.03125):
// 256x256 tile, BK=32, 8 waves, wave tile 128x64.
// A: bf16 GLL16, super-row swizzle. B: f32 weights GLL16'd directly,
// converted f32->bf16 on the LDS->reg path via v_cvt_pk_bf16_f32
// (1 op / 2 values; was 7-op pack2 -> VALU was the critical path).
// LDS: 2 bufs x (A 16KB + B 32KB) = 96KB. One super-phase per tile:
//   reads ; LGKM0 ; BAR ; stage(T+2) ; 32 MFMA ; VM6 ; BAR
// =======================================================================
template <int NT, int SPLIT>
__device__ __forceinline__ void gemm2f(const u16* __restrict__ A0,
                                       const u16* __restrict__ A1,
                                       const float* __restrict__ B0,
                                       const float* __restrict__ B1,
                                       u16* lds, f32x4 (&acc)[8][4], const int t) {
  const int w = t >> 6, l = t & 63;
  const int wr = (w >> 2) << 7;       // 0 / 128
  const int wc = (w & 3) << 6;        // 0..192
  const int lr = l & 15, c4 = l >> 4;

  // --- A read constants (u16 units) ---
  const int aphys = (((lr & 1) << 2) | c4) ^ ((lr >> 1) & 7);
  const int ard = wr * 32 + ((lr >> 1) << 6) + (aphys << 3);   // + mf*512 + buf*24576
  // --- B read constants (u32 units) ---
  const int bp0 = ((c4 << 1)) ^ (lr & 7);
  const int bp1 = ((c4 << 1) | 1) ^ (lr & 7);
  const int brd = (wc + lr) * 32;                               // + nf*512 + p*4
  // --- stage constants ---
  const int alog = (l & 7) ^ ((l >> 3) & 7);
  const size_t agsrc = (size_t)((w << 5) + ((l >> 3) << 1) + (alog >> 2)) * Ddim + ((alog & 3) << 3);
  const size_t bgsrc0 = (size_t)((w << 5) + (l >> 3)) * Ddim + (alog << 2);   // f32 elems

  auto stage = [&](int tt) {
    const u16* Asrc = (tt >= SPLIT) ? A1 : A0;
    const float* Bsrc = (tt >= SPLIT) ? B1 : B0;
    const int kk = (tt >= SPLIT) ? tt - SPLIT : tt;
    const int buf = tt & 1;
    u16* ad = lds + buf * 24576 + (w << 10);
    const u16* as = Asrc + agsrc + (kk << 5);
#pragma unroll
    for (int i = 0; i < 2; ++i)
      GLL16(as + (size_t)(i << 4) * Ddim, ad + (i << 9));
    u16* bd = lds + buf * 24576 + 8192 + (w << 11);
    const float* bs = Bsrc + bgsrc0 + (kk << 5);
#pragma unroll
    for (int i = 0; i < 4; ++i)
      GLL16(bs + (size_t)(i << 3) * Ddim, bd + (i << 9));
  };

  short8 af[8], bf[4];
  auto rdA = [&](int buf) {
    const u16* ab = lds + buf * 24576 + ard;
#pragma unroll
    for (int mf = 0; mf < 8; ++mf) af[mf] = *(const short8*)(ab + (mf << 9));
  };
  auto rdB = [&](int buf) {
    const u32* bb = (const u32*)(lds) + buf * 12288 + 4096 + brd;
#pragma unroll
    for (int nf = 0; nf < 4; ++nf) {
      const uint4 q0 = *(const uint4*)(bb + (nf << 9) + (bp0 << 2));
      const uint4 q1 = *(const uint4*)(bb + (nf << 9) + (bp1 << 2));
      uint4 o;
      o.x = cvtpk_u(q0.x, q0.y);
      o.y = cvtpk_u(q0.z, q0.w);
      o.z = cvtpk_u(q1.x, q1.y);
      o.w = cvtpk_u(q1.z, q1.w);
      bf[nf] = __builtin_bit_cast(short8, o);
    }
  };
  auto qall = [&]() {
    __builtin_amdgcn_s_setprio(1);
#pragma unroll
    for (int mf = 0; mf < 8; ++mf)
#pragma unroll
      for (int nf = 0; nf < 4; ++nf)
        acc[mf][nf] = __builtin_amdgcn_mfma_f32_16x16x32_bf16(af[mf], bf[nf], acc[mf][nf], 0, 0, 0);
    __builtin_amdgcn_s_setprio(0);
  };

  // prologue: tiles 0,1 staged; VM6 -> tile 0 landed (tile 1 may fly)
  stage(0); stage(1);
  VM6;
  RAW_BAR;

#pragma unroll 2
  for (int T = 0; T < NT - 2; ++T) {
    const int buf = T & 1;
    rdA(buf); rdB(buf);
    LGKM0;                 // this wave's reads of buf complete
    RAW_BAR;               // ALL waves' reads complete -> buf overwritable
    stage(T + 2);          // issue early: max latency cover
    qall();
    VM6;                   // tile T+1 fully landed; T+2's 6 stay in flight
    RAW_BAR;
  }
  {  // T = NT-2: no stage; drain so tile NT-1 ready
    const int buf = (NT - 2) & 1;
    rdA(buf); rdB(buf);
    LGKM0;
    RAW_BAR;
    qall();
    VM0;
    RAW_BAR;
  }
  {  // T = NT-1: pure compute
    const int buf = (NT - 1) & 1;
    rdA(buf); rdB(buf);
    qall();
  }
}

// =======================================================================
// Epilogue (two-pass, cvt_pk conversion): wave-private 8KB LDS [64][64]
// slot-XOR tile; per pass write 64 rows -> 8x {ds_read_b128 + store_dwordx4}.
// =======================================================================
template <bool GELU>
__device__ __forceinline__ void epi32(f32x4 (&acc)[8][4], const float* bias,
                                      u16* lds, u16* gout, int m_base, int n_base,
                                      const int t) {
  const int w = t >> 6, l = t & 63;
  const int lr = l & 15, c4 = l >> 4;
  u16* reg = lds + (w << 12);   // 4096 u16 = 8 KB per wave

  VM0;
  LGKM0;
  __builtin_amdgcn_sched_barrier(0);
  RAW_BAR;

  float bv[4];
#pragma unroll
  for (int nf = 0; nf < 4; ++nf) bv[nf] = bias[(nf << 4) + lr];

  const int g = l >> 3;
  const int phys = ((l & 7) ^ g) << 3;

#pragma unroll
  for (int pass = 0; pass < 2; ++pass) {
#pragma unroll
    for (int mf = 0; mf < 4; ++mf) {
      const int MF = pass * 4 + mf;
#pragma unroll
      for (int nf = 0; nf < 4; ++nf) {
        const int slot = (nf << 1) + (lr >> 3);
        const int bis = (lr & 7);
#pragma unroll
        for (int j = 0; j < 4; j += 2) {
          float va = acc[MF][nf][j] + bv[nf];
          float vb = acc[MF][nf][j + 1] + bv[nf];
          if (GELU) { va = gelu_f(va); vb = gelu_f(vb); }
          const u32 p = cvtpk(va, vb);
          const int row0 = (mf << 4) + (c4 << 2) + j;   // 0..63
          const int row1 = row0 + 1;
          reg[row0 * 64 + ((slot ^ (row0 & 7)) << 3) + bis] = (u16)p;
          reg[row1 * 64 + ((slot ^ (row1 & 7)) << 3) + bis] = (u16)(p >> 16);
        }
      }
    }
    LGKM0;
#pragma unroll
    for (int r = 0; r < 8; ++r) {
      const int row = (r << 3) + g;
      short8 v = *(const short8*)(reg + row * 64 + phys);
      *(short8*)(gout + (size_t)(m_base + pass * 64 + row) * Ddim + n_base + ((l & 7) << 3)) = v;
    }
    LGKM0;   // reads retired before next pass overwrites (WAR)
  }
}

// block decode: 1200 blocks = 100 experts x (4m x 3n); bijective XCD swizzle.
__device__ __forceinline__ void decode8(int bid, int& e, int& m0, int& n0) {
  const int s = (bid & 7) * 150 + (bid >> 3);   // 0..1199
  e = s / 12;
  const int r = s % 12;
  m0 = (r & 3) << 8;
  n0 = (r >> 2) << 8;
}

// ---------------- kernel A: h = gelu(x @ w1^T + b1), w1 f32 direct ----------------
__global__ __launch_bounds__(512, 2) void k_h13(const u16* __restrict__ xb,
                                                const float* __restrict__ w1,
                                                const float* __restrict__ b1,
                                                u16* __restrict__ hout) {
  __shared__ __align__(16) u16 lds[49152];   // 96 KB
  int e, m0, n0;
  decode8(blockIdx.x, e, m0, n0);
  const int t = threadIdx.x;
  f32x4 acc[8][4] = {};
  gemm2f<24, 24>(xb + (size_t)m0 * Ddim, nullptr,
                 w1 + (size_t)e * DD + (size_t)n0 * Ddim, nullptr, lds, acc, t);

  const int w = t >> 6;
  const int wr = (w >> 2) << 7, wc = (w & 3) << 6;
  epi32<true>(acc, b1 + (size_t)e * Ddim + n0 + wc, lds,
              hout + (size_t)e * Mdim * Ddim, m0 + wr, n0 + wc, t);
}

// ---------------- kernel B: x@wl^T + h@w2^T + biases -> bf16 tbuf ----------------
__global__ __launch_bounds__(512, 2) void k_out13(const u16* __restrict__ xb,
                                                  const u16* __restrict__ hbuf,
                                                  const float* __restrict__ wl,
                                                  const float* __restrict__ b_lin,
                                                  const float* __restrict__ w2,
                                                  const float* __restrict__ b2,
                                                  u16* __restrict__ tout) {
  __shared__ __align__(16) u16 lds[49152];   // 96 KB
  int e, m0, n0;
  decode8(blockIdx.x, e, m0, n0);
  const int t = threadIdx.x;
  f32x4 acc[8][4] = {};
  gemm2f<48, 24>(xb + (size_t)m0 * Ddim,
                 hbuf + (size_t)e * Mdim * Ddim + (size_t)m0 * Ddim,
                 wl + (size_t)e * DD + (size_t)n0 * Ddim,
                 w2 + (size_t)e * DD + (size_t)n0 * Ddim, lds, acc, t);

  const int w = t >> 6, l = t & 63;
  const int wr = (w >> 2) << 7, wc = (w & 3) << 6;
  const int lr = l & 15;
  const float* bm = b2 + (size_t)e * Ddim + n0 + wc;
#pragma unroll
  for (int nf = 0; nf < 4; ++nf) {
    const float bmv = bm[(nf << 4) + lr];
#pragma unroll
    for (int mf = 0; mf < 8; ++mf)
#pragma unroll
      for (int j = 0; j < 4; ++j) acc[mf][nf][j] += bmv;
  }
  epi32<false>(acc, b_lin + (size_t)e * Ddim + n0 + wc, lds,
               tout + (size_t)e * Mdim * Ddim, m0 + wr, n0 + wc, t);
}

// ---------------- transpose [E][M*D] -> [M*D][E] (bf16 tbuf) ----------------
__global__ __launch_bounds__(256) void k_tr_bf(const u16* __restrict__ tbuf,
                                               float* __restrict__ out) {
  __shared__ __align__(16) u16 tile[100 * 260];
  const int t = threadIdx.x;
  const size_t MD = (size_t)Mdim * Ddim;
  const size_t md0 = (size_t)blockIdx.x * 256;
#pragma unroll
  for (int p = 0; p < 25; ++p) {
    const int e = p * 4 + (t >> 6);
    const int c = (t & 63) * 4;
    uint2 v = *(const uint2*)(tbuf + (size_t)e * MD + md0 + c);
    *(uint2*)(&tile[e * 260 + c]) = v;
  }
  __syncthreads();
  const size_t obase = md0 * 100;
#pragma unroll 5
  for (int i = 0; i < 100; ++i) {
    const int flat = t + i * 256;                     // < 25600
    const int mo = (int)(((u32)flat * 5243u) >> 19);  // /100
    const int e = flat - mo * 100;
    out[obase + flat] = bf2f(tile[e * 260 + mo]);
  }
}

// =======================================================================
// Legacy fallback (tiny workspace): 2-barrier loop, f32 weights reg-staged,
// direct strided writes, chunked over experts. Slow but correct.
// =======================================================================
__device__ __forceinline__ void gemm_phase_f32(const u16* __restrict__ Ag,
                                               const float* __restrict__ Wg,
                                               u16* As, u16* Bs, f32x4 (&acc)[4][4], int t) {
  const int w = t >> 6, l = t & 63;
  const int lrow = l & 15, lk = (l >> 4) << 3;
  const int wr = ((w >> 1) << 6), wc = ((w & 1) << 6);
  for (int kt = 0; kt < Ddim; kt += 32) {
#pragma unroll
    for (int i = 0; i < 2; ++i) {
      GLL16(Ag + (size_t)((w << 5) + (i << 4) + (l >> 2)) * Ddim + kt + ((l & 3) << 3),
            As + (((w << 5) + (i << 4)) << 5));
    }
    {
      const int r = t >> 1, c = (t & 1) << 4;
      const float* src = Wg + (size_t)r * Ddim + kt + c;
      const float4 f0 = *(const float4*)(src);
      const float4 f1 = *(const float4*)(src + 4);
      const float4 f2 = *(const float4*)(src + 8);
      const float4 f3 = *(const float4*)(src + 12);
      uint4 v0, v1;
      v0.x = pack2(f0.x, f0.y); v0.y = pack2(f0.z, f0.w);
      v0.z = pack2(f1.x, f1.y); v0.w = pack2(f1.z, f1.w);
      v1.x = pack2(f2.x, f2.y); v1.y = pack2(f2.z, f2.w);
      v1.z = pack2(f3.x, f3.y); v1.w = pack2(f3.z, f3.w);
      *(uint4*)(&Bs[r * 32 + c]) = v0;
      *(uint4*)(&Bs[r * 32 + c + 8]) = v1;
    }
    __syncthreads();
    short8 af[4], bfr[4];
#pragma unroll
    for (int f = 0; f < 4; ++f) {
      af[f]  = *(const short8*)(&As[(wr + f * 16 + lrow) * 32 + lk]);
      bfr[f] = *(const short8*)(&Bs[(wc + f * 16 + lrow) * 32 + lk]);
    }
#pragma unroll
    for (int fm = 0; fm < 4; ++fm)
#pragma unroll
      for (int fn = 0; fn < 4; ++fn)
        acc[fm][fn] = __builtin_amdgcn_mfma_f32_16x16x32_bf16(af[fm], bfr[fn], acc[fm][fn], 0, 0, 0);
    __syncthreads();
  }
}

__global__ __launch_bounds__(256) void k_h2(const u16* __restrict__ xb,
                                            const float* __restrict__ w1,
                                            const float* __restrict__ b1,
                                            u16* __restrict__ hout, int e_base) {
  __shared__ __align__(16) u16 As[128 * 32];
  __shared__ __align__(16) u16 Bs[128 * 32];
  const int el = blockIdx.x / 48, r = blockIdx.x % 48;
  const int m0 = (r / 6) * 128, n0 = (r % 6) * 128;
  const int e = e_base + el;
  const int t = threadIdx.x, l = t & 63, wv = t >> 6;
  const int wr = (wv >> 1) * 64, wc = (wv & 1) * 64, lrow = l & 15;
  f32x4 acc[4][4] = {};
  gemm_phase_f32(xb + (size_t)m0 * Ddim, w1 + (size_t)e * DD + (size_t)n0 * Ddim, As, Bs, acc, t);
  const float* bias = b1 + (size_t)e * Ddim + n0;
  u16* hb = hout + (size_t)el * Mdim * Ddim;
#pragma unroll
  for (int fm = 0; fm < 4; ++fm) {
    const int mb = m0 + wr + fm * 16 + ((l >> 4) << 2);
#pragma unroll
    for (int fn = 0; fn < 4; ++fn) {
      const int nc = wc + fn * 16 + lrow;
      const float bv = bias[nc];
#pragma unroll
      for (int j = 0; j < 4; ++j) {
        float v = acc[fm][fn][j] + bv;
        v = 0.5f * v * (1.0f + erff(v * 0.7071067811865475f));
        hb[(size_t)(mb + j) * Ddim + n0 + nc] = f2bf(v);
      }
    }
  }
}

__global__ __launch_bounds__(256) void k_out2(
    const u16* __restrict__ xb, const u16* __restrict__ hbuf,
    const float* __restrict__ wl, const float* __restrict__ b_lin,
    const float* __restrict__ w2, const float* __restrict__ b2,
    float* __restrict__ out, int e_base) {
  __shared__ __align__(16) u16 As[128 * 32];
  __shared__ __align__(16) u16 Bs[128 * 32];
  const int el = blockIdx.x / 48, r = blockIdx.x % 48;
  const int m0 = (r / 6) * 128, n0 = (r % 6) * 128;
  const int e = e_base + el;
  const int t = threadIdx.x, l = t & 63, wv = t >> 6;
  const int wr = (wv >> 1) * 64, wc = (wv & 1) * 64, lrow = l & 15;
  f32x4 acc[4][4] = {};
  gemm_phase_f32(xb + (size_t)m0 * Ddim, wl + (size_t)e * DD + (size_t)n0 * Ddim, As, Bs, acc, t);
  gemm_phase_f32(hbuf + (size_t)el * Mdim * Ddim + (size_t)m0 * Ddim,
                 w2 + (size_t)e * DD + (size_t)n0 * Ddim, As, Bs, acc, t);
  const float* bl = b_lin + (size_t)e * Ddim + n0;
  const float* bm = b2 + (size_t)e * Ddim + n0;
#pragma unroll
  for (int fm = 0; fm < 4; ++fm) {
    const int mb = m0 + wr + fm * 16 + ((l >> 4) << 2);
#pragma unroll
    for (int fn = 0; fn < 4; ++fn) {
      const int nc = wc + fn * 16 + lrow;
      const float bv = bl[nc] + bm[nc];
#pragma unroll
      for (int j = 0; j < 4; ++j)
        out[((size_t)(mb + j) * Ddim + n0 + nc) * Edim + e] = acc[fm][fn][j] + bv;
    }
  }
}

extern "C" void kernel_launch(void* const* d_in, const int* in_sizes, int n_in,
                              void* d_out, int out_size, void* d_ws, size_t ws_size,
                              hipStream_t stream) {
  const float* x     = (const float*)d_in[0];
  const float* w_lin = (const float*)d_in[1];
  const float* b_lin = (const float*)d_in[2];
  const float* w1    = (const float*)d_in[3];
  const float* b1    = (const float*)d_in[4];
  const float* w2    = (const float*)d_in[5];
  const float* b2    = (const float*)d_in[6];
  float* out = (float*)d_out;

  const size_t MD = (size_t)Mdim * Ddim;          // 786432
  const size_t xb_b = MD * 2;                     // 1.57 MB
  const size_t h_b  = (size_t)Edim * MD * 2;      // 157 MB
  const size_t tb_b = h_b;                        // 157 MB

  char* base = (char*)d_ws;
  u16* xb = (u16*)base;
  k_cvt<<<dim3((u32)(MD / 1024)), dim3(256), 0, stream>>>(x, xb);

  if (ws_size >= xb_b + h_b + tb_b) {
    // Preferred (316 MB): f32-weight-direct GEMMs (no converter passes)
    u16* hbuf = (u16*)(base + xb_b);
    u16* tbuf = (u16*)(base + xb_b + h_b);
    k_h13<<<dim3(1200), dim3(512), 0, stream>>>(xb, w1, b1, hbuf);
    k_out13<<<dim3(1200), dim3(512), 0, stream>>>(xb, hbuf, w_lin, b_lin, w2, b2, tbuf);
    k_tr_bf<<<dim3((u32)(MD / 256)), dim3(256), 0, stream>>>(tbuf, out);
  } else {
    // Chunked fallback: direct strided writes (slow but correct)
    size_t avail = ws_size > xb_b ? ws_size - xb_b : 0;
    int EC = (int)(avail / (MD * 2));
    if (EC < 1) EC = 1;
    if (EC > Edim) EC = Edim;
    u16* hbuf = (u16*)(base + xb_b);
    for (int e0 = 0; e0 < Edim; e0 += EC) {
      int ne = (Edim - e0) < EC ? (Edim - e0) : EC;
      k_h2<<<dim3(ne * 48), dim3(256), 0, stream>>>(xb, w1, b1, hbuf, e0);
      k_out2<<<dim3(ne * 48), dim3(256), 0, stream>>>(xb, hbuf, w_lin, b_lin, w2, b2,
                                                      out, e0);
    }
  }
}